// Round 11
// baseline (276.113 us; speedup 1.0000x reference)
//
#include <hip/hip_runtime.h>
#include <hip/hip_bf16.h>

// Problem: B=16, S=4096, H=1024
//   energy = tanh(x @ W^T + b); scores = softmax(energy, axis=S); out = sum_S scores*x
// GEMM view: M = B*S = 65536, N = H = 1024, K = H = 1024.
#define Bsz  16
#define Sdim 4096
#define Hdim 1024
#define Mtot (Bsz * Sdim)   // 65536
#define Kdim Hdim
#define Ndim Hdim

#define BM2 256
#define BN2 256
#define MT2 (Mtot / BM2)    // 256
#define NT2 (Ndim / BN2)    // 4
#define NKT32 (Kdim / 32)   // 32 K-tiles

typedef short s16x8 __attribute__((ext_vector_type(8)));
typedef float f32x4 __attribute__((ext_vector_type(4)));

__device__ __forceinline__ unsigned short f2bf(float f) {
  __hip_bfloat16 h = __float2bfloat16(f);
  unsigned short u;
  __builtin_memcpy(&u, &h, 2);
  return u;
}
__device__ __forceinline__ s16x8 cvt8(float4 u, float4 v) {
  s16x8 r;
  r[0] = (short)f2bf(u.x); r[1] = (short)f2bf(u.y);
  r[2] = (short)f2bf(u.z); r[3] = (short)f2bf(u.w);
  r[4] = (short)f2bf(v.x); r[5] = (short)f2bf(v.y);
  r[6] = (short)f2bf(v.z); r[7] = (short)f2bf(v.w);
  return r;
}

// async global->LDS, 16B per lane; LDS dest is wave-uniform base + lane*16
__device__ __forceinline__ void gload_lds16(const unsigned short* g, unsigned short* l) {
  __builtin_amdgcn_global_load_lds(
      (const __attribute__((address_space(1))) unsigned int*)g,
      (__attribute__((address_space(3))) unsigned int*)l,
      16, 0, 0);
}

// ---- kernel 1: W fp32 [N][K] -> row-major bf16 Wb (2 MB) ----
__global__ __launch_bounds__(256) void wconv_kernel(const float* __restrict__ W,
                                                    unsigned short* __restrict__ Wb) {
  int i = blockIdx.x * 256 + threadIdx.x;
  float4 v = reinterpret_cast<const float4*>(W)[i];
  ushort4 o;
  o.x = f2bf(v.x); o.y = f2bf(v.y); o.z = f2bf(v.z); o.w = f2bf(v.w);
  reinterpret_cast<ushort4*>(Wb)[i] = o;
}

// =====================================================================
// kernel 2: 256^2, BK=32, R5's proven schedule, X fp32->bf16 fused into
// A-staging with DEEP prefetch (the R10 fix):
//   tile t ph0: stage B(t+1) [gload_lds], THEN issue A-fp32 loads L(t+2)
//               into a named reg set (gEv/gOd alternating, rule #20).
//   tile t ph1: cvt + ds_write D(t+1) from the OTHER set (loaded one full
//               tile earlier -> ~4000 cy cover >> HBM latency; the
//               ds_write's auto-vmcnt wait is free).
// vmcnt never drains in steady state: B staged before L => vmcnt(4) at
// ph1-end retires exactly B(t+1), leaves the 4 A-loads flying.
// Write-slot safety: D(t+1) -> slot (t+1)&1 written at t ph1; that
// slot's last readers (tile t-1) passed END(t-1) two barriers earlier;
// writer's MID-ph1 lgkmcnt(0) drains the write before END(t), so tile
// t+1's readers (after END(t)) see complete data.
// Swizzle identical to R5/R10 (0 bank conflicts measured on both paths).
// =====================================================================
__global__ __launch_bounds__(512, 2) void attn_main(
    const float* __restrict__ X,            // [Mtot][Kdim] fp32
    const unsigned short* __restrict__ Wb,  // [Ndim][Kdim] bf16
    const float* __restrict__ bias,         // [Ndim]
    float* __restrict__ lpart,              // [MT2][Ndim]
    float* __restrict__ cpart) {            // [MT2][Ndim]
  __shared__ unsigned short Abf[2][BM2 * 32];  // 32 KB
  __shared__ unsigned short Bbf[2][BN2 * 32];  // 32 KB
  __shared__ float red[2][2][BN2];             // 4 KB -> 68 KB total

  // XCD-chunked bijective swizzle (nwg=1024, 1024%8==0)
  int bid = blockIdx.x;
  int swz = (bid & 7) * (MT2 * NT2 / 8) + (bid >> 3);
  const int mt = swz >> 2;
  const int nt = swz & 3;
  const int m0 = mt * BM2;
  const int n0 = nt * BN2;

  const int tid = threadIdx.x;
  const int l   = tid & 63;
  const int w   = tid >> 6;
  const int wm  = w >> 2;         // 0..1 (M half)
  const int wn  = w & 3;          // 0..3 (N quarter)
  const int lr  = l & 15;
  const int lk  = l >> 4;

  f32x4 acc[8][4];
#pragma unroll
  for (int i = 0; i < 8; i++)
#pragma unroll
    for (int j = 0; j < 4; j++) acc[i][j] = (f32x4){0.f, 0.f, 0.f, 0.f};

  // ---- A staging: fp32 source + swizzled LDS write addresses (R10-proven) ----
  const int ra = tid >> 1;              // row 0..255
  const int ch = tid & 1;               // 16-elem half
  const float* gaP = X + (size_t)(m0 + ra) * Kdim + ch * 16;
  const int xa = (ra >> 1) & 3;         // swizzle key
  const int swA0 = ra * 32 + (((ch * 2 + 0) ^ xa) << 3);
  const int swA1 = ra * 32 + (((ch * 2 + 1) ^ xa) << 3);

  // ---- B staging source (inverse-swizzled, R5-proven) ----
  const int srow = w * 16 + (l >> 2);
  const int scol = (((l & 3) ^ ((l >> 3) & 3)) << 3);
  const unsigned short* srcB0 = Wb + (size_t)(n0 + srow) * Kdim + scol;

  // ---- fragment read offsets (R5-proven zero-conflict pattern) ----
  int offA[2][4], offB[4];
#pragma unroll
  for (int mh = 0; mh < 2; mh++)
#pragma unroll
    for (int j = 0; j < 4; j++) {
      const int r = wm * 128 + mh * 64 + j * 16 + lr;
      offA[mh][j] = r * 32 + ((lk ^ ((r >> 1) & 3)) << 3);
    }
#pragma unroll
  for (int n = 0; n < 4; n++) {
    const int rn = wn * 64 + n * 16 + lr;
    offB[n] = rn * 32 + ((lk ^ ((rn >> 1) & 3)) << 3);
  }

#define STAGE_B(slot, tp) do {                                          \
    unsigned short* d = &Bbf[slot][w * 512];                            \
    const unsigned short* g = srcB0 + (size_t)(tp) * 32;                \
    gload_lds16(g, d);                                                  \
    gload_lds16(g + (size_t)128 * Kdim, d + 4096);                      \
  } while (0)

#define MID_BARRIER() do {                                   \
    asm volatile("" ::: "memory");                           \
    __builtin_amdgcn_s_barrier();                            \
    asm volatile("s_waitcnt lgkmcnt(0)" ::: "memory");       \
    __builtin_amdgcn_sched_barrier(0);                       \
  } while (0)
#define END_BARRIER() do {                                   \
    asm volatile("" ::: "memory");                           \
    __builtin_amdgcn_s_barrier();                            \
  } while (0)
#define VM4() asm volatile("s_waitcnt vmcnt(4)" ::: "memory")
#define VM0() asm volatile("s_waitcnt vmcnt(0)" ::: "memory")

#define RD_A(SLOT, MH) do {                                              \
    _Pragma("unroll")                                                    \
    for (int j = 0; j < 4; ++j) af[j] = *(const s16x8*)&Abf[SLOT][offA[MH][j]]; \
  } while (0)
#define RD_Bf(SLOT) do {                                                 \
    _Pragma("unroll")                                                    \
    for (int n = 0; n < 4; ++n) bf[n] = *(const s16x8*)&Bbf[SLOT][offB[n]]; \
  } while (0)
#define MFMA16(BASE) do {                                                \
    __builtin_amdgcn_s_setprio(1);                                       \
    _Pragma("unroll")                                                    \
    for (int j = 0; j < 4; ++j)                                          \
      _Pragma("unroll")                                                  \
      for (int n = 0; n < 4; ++n)                                        \
        acc[(BASE) + j][n] = __builtin_amdgcn_mfma_f32_16x16x32_bf16(    \
            af[j], bf[n], acc[(BASE) + j][n], 0, 0, 0);                  \
    __builtin_amdgcn_s_setprio(0);                                       \
  } while (0)

  float4 gEv0, gEv1, gEv2, gEv3;   // A fp32 data for even-numbered target tiles
  float4 gOd0, gOd1, gOd2, gOd3;   // ... odd-numbered target tiles

  // ---- prologue: D(0)->slot0 (direct), B(0)->slot0, issue L(1)->gOd ----
  {
    float4 a0 = *(const float4*)(gaP + 0);
    float4 a1 = *(const float4*)(gaP + 4);
    float4 a2 = *(const float4*)(gaP + 8);
    float4 a3 = *(const float4*)(gaP + 12);
    STAGE_B(0, 0);
    gOd0 = *(const float4*)(gaP + 32);
    gOd1 = *(const float4*)(gaP + 36);
    gOd2 = *(const float4*)(gaP + 40);
    gOd3 = *(const float4*)(gaP + 44);
    *(s16x8*)&Abf[0][swA0] = cvt8(a0, a1);   // auto-waits a0..a3
    *(s16x8*)&Abf[0][swA1] = cvt8(a2, a3);
    VM4();                                   // retire B(0); gOd still flying
    asm volatile("s_waitcnt lgkmcnt(0)" ::: "memory");  // D(0) writes done
    END_BARRIER();
  }

  s16x8 bf[4];

  // ---- main loop: 16 iterations x 2 tiles (even t0 = 2u, odd t1 = 2u+1) ----
  for (int u = 0; u < 16; ++u) {
    const int t0 = 2 * u;
    const bool more = (u < 15);
    s16x8 af[4];

    // ======== tile t0 (even): cur = slot0, nxt = slot1 ========
    // ph0
    RD_A(0, 0); RD_Bf(0);
    STAGE_B(1, t0 + 1);                        // B(t0+1) -> slot1 (always: t0+1 <= 31)
    if (more) {                                // L(t0+2) -> gEv
      const float* ap = gaP + (t0 + 2) * 32;
      gEv0 = *(const float4*)(ap + 0);
      gEv1 = *(const float4*)(ap + 4);
      gEv2 = *(const float4*)(ap + 8);
      gEv3 = *(const float4*)(ap + 12);
    }
    MID_BARRIER();
    MFMA16(0);
    END_BARRIER();
    // ph1
    RD_A(0, 1);
    *(s16x8*)&Abf[1][swA0] = cvt8(gOd0, gOd1); // D(t0+1); data 1 tile old -> free wait
    *(s16x8*)&Abf[1][swA1] = cvt8(gOd2, gOd3);
    MID_BARRIER();
    MFMA16(4);
    if (more) VM4(); else VM0();               // retire B(t0+1); leave L flying
    END_BARRIER();

    // ======== tile t1 (odd): cur = slot1, nxt = slot0 ========
    // ph0
    RD_A(1, 0); RD_Bf(1);
    if (more) {
      STAGE_B(0, t0 + 2);                      // B(t1+1)
      const float* ap = gaP + (t0 + 3) * 32;   // L(t1+2) -> gOd
      gOd0 = *(const float4*)(ap + 0);
      gOd1 = *(const float4*)(ap + 4);
      gOd2 = *(const float4*)(ap + 8);
      gOd3 = *(const float4*)(ap + 12);
    }
    MID_BARRIER();
    MFMA16(0);
    END_BARRIER();
    // ph1
    RD_A(1, 1);
    if (more) {
      *(s16x8*)&Abf[0][swA0] = cvt8(gEv0, gEv1);  // D(t1+1)
      *(s16x8*)&Abf[0][swA1] = cvt8(gEv2, gEv3);
    }
    MID_BARRIER();
    MFMA16(4);
    if (more) VM4();                           // retire B(t1+1); leave L flying
    END_BARRIER();
  }

  // ---- epilogue: e = tanh(acc+bias); l = sum exp(e), c = sum exp(e)*x ----
  // C/D layout: col = lane&15, row = (lane>>4)*4 + reg.
  // acc[m8] rows: wm*128 + (m8>>2)*64 + (m8&3)*16. tanh bounded -> no max sub.
  float lsum[4], csum[4];
#pragma unroll
  for (int nr = 0; nr < 4; nr++) {
    const int o = n0 + wn * 64 + nr * 16 + lr;
    const float bv = bias[o];
    float lacc = 0.f, cacc = 0.f;
#pragma unroll
    for (int m8 = 0; m8 < 8; m8++) {
      const int sr = m0 + wm * 128 + (m8 >> 2) * 64 + (m8 & 3) * 16 + lk * 4;
#pragma unroll
      for (int r = 0; r < 4; r++) {
        float e  = acc[m8][nr][r] + bv;
        float t  = __expf(2.f * e);
        float th = 1.f - __fdividef(2.f, t + 1.f);  // tanh(e); e bounded ~[-7,7]
        float sc = __expf(th);                      // in [0.37, 2.72]
        float xv = X[(size_t)(sr + r) * Kdim + o];  // fp32, L2-warm
        lacc += sc;
        cacc += sc * xv;
      }
    }
    lacc += __shfl_xor(lacc, 16); lacc += __shfl_xor(lacc, 32);
    cacc += __shfl_xor(cacc, 16); cacc += __shfl_xor(cacc, 32);
    lsum[nr] = lacc; csum[nr] = cacc;
  }

  if (lk == 0) {
#pragma unroll
    for (int nr = 0; nr < 4; nr++) {
      red[wm][0][wn * 64 + nr * 16 + lr] = lsum[nr];
      red[wm][1][wn * 64 + nr * 16 + lr] = csum[nr];
    }
  }
  __syncthreads();
  if (tid < BN2) {
    float L = red[0][0][tid] + red[1][0][tid];
    float C = red[0][1][tid] + red[1][1][tid];
    lpart[(size_t)mt * Ndim + n0 + tid] = L;
    cpart[(size_t)mt * Ndim + n0 + tid] = C;
  }
}

// ---- kernel 3: combine s-chunks -> out[b][o] ----
__global__ __launch_bounds__(256) void finalize_kernel(const float* __restrict__ lpart,
                                                       const float* __restrict__ cpart,
                                                       float* __restrict__ out, int chunks) {
  int i = blockIdx.x * 256 + threadIdx.x;
  int b = i >> 10, o = i & 1023;
  float L = 0.f, C = 0.f;
  for (int sc = 0; sc < chunks; ++sc) {
    size_t idx = (size_t)(b * chunks + sc) * Ndim + o;
    L += lpart[idx];
    C += cpart[idx];
  }
  out[i] = C / L;
}

extern "C" void kernel_launch(void* const* d_in, const int* in_sizes, int n_in,
                              void* d_out, int out_size, void* d_ws, size_t ws_size,
                              hipStream_t stream) {
  const float* X    = (const float*)d_in[0];
  const float* W    = (const float*)d_in[1];
  const float* bias = (const float*)d_in[2];
  float* out = (float*)d_out;

  // ws: Wb bf16 (2 MB) | lpart f32 [256*1024] (1 MB) | cpart (1 MB)
  unsigned short* Wb = (unsigned short*)d_ws;
  float* lpart = (float*)((char*)d_ws + (size_t)Ndim * Kdim * 2);
  float* cpart = lpart + (size_t)MT2 * Ndim;

  wconv_kernel<<<dim3(Ndim * Kdim / 1024), dim3(256), 0, stream>>>(W, Wb);
  attn_main<<<dim3(MT2 * NT2), dim3(512), 0, stream>>>(X, Wb, bias, lpart, cpart);
  finalize_kernel<<<dim3(Bsz * Hdim / 256), dim3(256), 0, stream>>>(lpart, cpart, out,
                                                                    Sdim / BM2);
}

// Round 12
// 239.913 us; speedup vs baseline: 1.1509x; 1.1509x over previous
//
#include <hip/hip_runtime.h>
#include <hip/hip_bf16.h>

// Problem: B=16, S=4096, H=1024
//   energy = tanh(x @ W^T + b); scores = softmax(energy, axis=S); out = sum_S scores*x
// GEMM view: M = B*S = 65536, N = H = 1024, K = H = 1024.
#define Bsz  16
#define Sdim 4096
#define Hdim 1024
#define Mtot (Bsz * Sdim)   // 65536
#define Kdim Hdim
#define Ndim Hdim

// ---- tile geometry (256^2, BK=64, 8 waves 2Mx4N, R5-proven 4-phase) ----
#define BM2 256
#define BN2 256
#define MT2 (Mtot / BM2)    // 256
#define NT2 (Ndim / BN2)    // 4
#define NKT64 (Kdim / 64)   // 16 K-tiles

typedef short s16x8 __attribute__((ext_vector_type(8)));
typedef float f32x4 __attribute__((ext_vector_type(4)));

__device__ __forceinline__ unsigned short f2bf(float f) {
  __hip_bfloat16 h = __float2bfloat16(f);
  unsigned short u;
  __builtin_memcpy(&u, &h, 2);
  return u;
}
__device__ __forceinline__ float bf2f(unsigned short u) {
  __hip_bfloat16 h;
  __builtin_memcpy(&h, &u, 2);
  return __bfloat162float(h);
}
__device__ __forceinline__ s16x8 cvt8(float4 u, float4 v) {
  s16x8 r;
  r[0] = (short)f2bf(u.x); r[1] = (short)f2bf(u.y);
  r[2] = (short)f2bf(u.z); r[3] = (short)f2bf(u.w);
  r[4] = (short)f2bf(v.x); r[5] = (short)f2bf(v.y);
  r[6] = (short)f2bf(v.z); r[7] = (short)f2bf(v.w);
  return r;
}

// async global->LDS, 16B per lane; LDS dest is wave-uniform base + lane*16
__device__ __forceinline__ void gload_lds16(const unsigned short* g, unsigned short* l) {
  __builtin_amdgcn_global_load_lds(
      (const __attribute__((address_space(1))) unsigned int*)g,
      (__attribute__((address_space(3))) unsigned int*)l,
      16, 0, 0);
}

// ---- kernel 0: merged conversion prepass (one dispatch) ----
// blocks [0, 32768): X fp32 [M][K] -> bf16 Xb (8 elems/thread)
// blocks [32768, 36864): W fp32 [N][K] -> bf16 Wb (4 elems/thread)
#define XCONV_BLKS (Mtot * (Kdim / 8) / 256)   // 32768
#define WCONV_BLKS (Ndim * Kdim / 1024)        // 4096
__global__ __launch_bounds__(256) void conv_kernel(const float* __restrict__ X,
                                                   const float* __restrict__ W,
                                                   unsigned short* __restrict__ Xb,
                                                   unsigned short* __restrict__ Wb) {
  int b = blockIdx.x;
  if (b < XCONV_BLKS) {
    size_t i = (size_t)b * 256 + threadIdx.x;
    float4 u = reinterpret_cast<const float4*>(X)[2 * i];
    float4 v = reinterpret_cast<const float4*>(X)[2 * i + 1];
    reinterpret_cast<s16x8*>(Xb)[i] = cvt8(u, v);
  } else {
    int i = (b - XCONV_BLKS) * 256 + threadIdx.x;
    float4 v = reinterpret_cast<const float4*>(W)[i];
    ushort4 o;
    o.x = f2bf(v.x); o.y = f2bf(v.y); o.z = f2bf(v.z); o.w = f2bf(v.w);
    reinterpret_cast<ushort4*>(Wb)[i] = o;
  }
}

// =====================================================================
// kernel 2: R5-proven best (session minimum): 256^2, BK=64, 4 phases per
// K-tile, 2-slot x 2-kk LDS ring, counted vmcnt(2)/vmcnt(4), setprio,
// zero-conflict swizzle. Measured: attn 183-188 us, MfmaUtil ~31%,
// SQ_LDS_BANK_CONFLICT = 0, no spill. Six structural variants (1/2/4/8
// phases, B-in-regs, derived-waits 8-phase, fused cvt) all measured
// equal or worse -> this is the structural plateau for this problem.
// =====================================================================
__global__ __launch_bounds__(512, 2) void attn_main(
    const unsigned short* __restrict__ Xb,  // [Mtot][Kdim] bf16
    const unsigned short* __restrict__ Wb,  // [Ndim][Kdim] bf16
    const float* __restrict__ bias,         // [Ndim]
    float* __restrict__ lpart,              // [MT2][Ndim]
    float* __restrict__ cpart) {            // [MT2][Ndim]
  __shared__ unsigned short Asl[2][2][BM2 * 32];  // [slot][kk][row*32+c] 64 KB
  __shared__ unsigned short Bsl[2][2][BN2 * 32];  // 64 KB
  __shared__ float red[2][2][BN2];                // 4 KB

  // XCD-chunked bijective swizzle (nwg=1024, 1024%8==0)
  int bid = blockIdx.x;
  int swz = (bid & 7) * (MT2 * NT2 / 8) + (bid >> 3);
  const int mt = swz >> 2;         // 0..255
  const int nt = swz & 3;          // 0..3
  const int m0 = mt * BM2;
  const int n0 = nt * BN2;

  const int tid  = threadIdx.x;
  const int l    = tid & 63;       // lane
  const int w    = tid >> 6;       // wave 0..7
  const int wm   = w >> 2;         // 0..1 (M half)
  const int wn   = w & 3;          // 0..3 (N quarter)
  const int lr   = l & 15;
  const int lk   = l >> 4;

  f32x4 acc[8][4];
#pragma unroll
  for (int i = 0; i < 8; i++)
#pragma unroll
    for (int j = 0; j < 4; j++) acc[i][j] = (f32x4){0.f, 0.f, 0.f, 0.f};

  // ---- staging source (inverse-swizzled global addresses) ----
  const int srow = w * 16 + (l >> 2);
  const int scol = (((l & 3) ^ ((l >> 3) & 3)) << 3);  // elements
  const unsigned short* srcA0 = Xb + (size_t)(m0 + srow) * Kdim + scol;
  const unsigned short* srcB0 = Wb + (size_t)(n0 + srow) * Kdim + scol;

  // ---- fragment read offsets (swizzled, within a [256][32] kk-subarray) ----
  int offA[2][4], offB[4];
#pragma unroll
  for (int mh = 0; mh < 2; mh++)
#pragma unroll
    for (int j = 0; j < 4; j++) {
      const int r = wm * 128 + mh * 64 + j * 16 + lr;
      offA[mh][j] = r * 32 + ((lk ^ ((r >> 1) & 3)) << 3);
    }
#pragma unroll
  for (int n = 0; n < 4; n++) {
    const int rn = wn * 64 + n * 16 + lr;
    offB[n] = rn * 32 + ((lk ^ ((rn >> 1) & 3)) << 3);
  }

#define STAGE_A(tp, kh) do {                                            \
    unsigned short* d = &Asl[(tp) & 1][kh][w * 512];                    \
    const unsigned short* g = srcA0 + (size_t)(tp) * 64 + (kh) * 32;    \
    gload_lds16(g, d);                                                  \
    gload_lds16(g + (size_t)128 * Kdim, d + 4096);                      \
  } while (0)
#define STAGE_B(tp, kh) do {                                            \
    unsigned short* d = &Bsl[(tp) & 1][kh][w * 512];                    \
    const unsigned short* g = srcB0 + (size_t)(tp) * 64 + (kh) * 32;    \
    gload_lds16(g, d);                                                  \
    gload_lds16(g + (size_t)128 * Kdim, d + 4096);                      \
  } while (0)

#define MID_BARRIER() do {                                   \
    asm volatile("" ::: "memory");                           \
    __builtin_amdgcn_s_barrier();                            \
    asm volatile("s_waitcnt lgkmcnt(0)" ::: "memory");       \
    __builtin_amdgcn_sched_barrier(0);                       \
  } while (0)
#define END_BARRIER() do {                                   \
    asm volatile("" ::: "memory");                           \
    __builtin_amdgcn_s_barrier();                            \
  } while (0)

  // ---- prologue: stage tile 0 fully (A-k0, B-k0 first), land A-k0/B-k0 ----
  STAGE_A(0, 0); STAGE_B(0, 0); STAGE_A(0, 1); STAGE_B(0, 1);
  asm volatile("s_waitcnt vmcnt(4)" ::: "memory");  // A-k0,B-k0 landed
  END_BARRIER();

  s16x8 bf0[4], bf1[4];

  // ---- main loop: 16 K-tiles x 4 phases ----
  for (int t = 0; t < NKT64; ++t) {
    const int s = t & 1;
    const unsigned short* As0 = Asl[s][0];
    const unsigned short* As1 = Asl[s][1];
    const unsigned short* Bs0 = Bsl[s][0];
    const unsigned short* Bs1 = Bsl[s][1];
    const int tp = t + 1;
    const bool more = (tp < NKT64);
    s16x8 af[4];

    // ===== phase 1: (mh0, kk0) — reads A(mh0,k0)+B(k0); stage A-k0(t+1) =====
#pragma unroll
    for (int j = 0; j < 4; ++j) af[j] = *(const s16x8*)&As0[offA[0][j]];
#pragma unroll
    for (int n = 0; n < 4; ++n) bf0[n] = *(const s16x8*)&Bs0[offB[n]];
    if (more) STAGE_A(tp, 0);
    MID_BARRIER();
    __builtin_amdgcn_s_setprio(1);
#pragma unroll
    for (int j = 0; j < 4; ++j)
#pragma unroll
      for (int n = 0; n < 4; ++n)
        acc[j][n] = __builtin_amdgcn_mfma_f32_16x16x32_bf16(af[j], bf0[n], acc[j][n], 0, 0, 0);
    __builtin_amdgcn_s_setprio(0);
    if (more) asm volatile("s_waitcnt vmcnt(2)" ::: "memory");  // lands A-k1,B-k1 of t
    else      asm volatile("s_waitcnt vmcnt(0)" ::: "memory");
    END_BARRIER();

    // ===== phase 2: (mh0, kk1) — reads A(mh0,k1)+B(k1); stage B-k0(t+1) =====
#pragma unroll
    for (int j = 0; j < 4; ++j) af[j] = *(const s16x8*)&As1[offA[0][j]];
#pragma unroll
    for (int n = 0; n < 4; ++n) bf1[n] = *(const s16x8*)&Bs1[offB[n]];
    if (more) STAGE_B(tp, 0);
    MID_BARRIER();
    __builtin_amdgcn_s_setprio(1);
#pragma unroll
    for (int j = 0; j < 4; ++j)
#pragma unroll
      for (int n = 0; n < 4; ++n)
        acc[j][n] = __builtin_amdgcn_mfma_f32_16x16x32_bf16(af[j], bf1[n], acc[j][n], 0, 0, 0);
    __builtin_amdgcn_s_setprio(0);
    END_BARRIER();

    // ===== phase 3: (mh1, kk0) — reads A(mh1,k0); B(k0) cached; stage A-k1(t+1) =====
#pragma unroll
    for (int j = 0; j < 4; ++j) af[j] = *(const s16x8*)&As0[offA[1][j]];
    if (more) STAGE_A(tp, 1);
    MID_BARRIER();
    __builtin_amdgcn_s_setprio(1);
#pragma unroll
    for (int j = 0; j < 4; ++j)
#pragma unroll
      for (int n = 0; n < 4; ++n)
        acc[4 + j][n] = __builtin_amdgcn_mfma_f32_16x16x32_bf16(af[j], bf0[n], acc[4 + j][n], 0, 0, 0);
    __builtin_amdgcn_s_setprio(0);
    END_BARRIER();

    // ===== phase 4: (mh1, kk1) — reads A(mh1,k1); B(k1) cached; stage B-k1(t+1) =====
#pragma unroll
    for (int j = 0; j < 4; ++j) af[j] = *(const s16x8*)&As1[offA[1][j]];
    if (more) STAGE_B(tp, 1);
    MID_BARRIER();
    __builtin_amdgcn_s_setprio(1);
#pragma unroll
    for (int j = 0; j < 4; ++j)
#pragma unroll
      for (int n = 0; n < 4; ++n)
        acc[4 + j][n] = __builtin_amdgcn_mfma_f32_16x16x32_bf16(af[j], bf1[n], acc[4 + j][n], 0, 0, 0);
    __builtin_amdgcn_s_setprio(0);
    if (more) asm volatile("s_waitcnt vmcnt(4)" ::: "memory");  // lands A-k0,B-k0 of t+1
    END_BARRIER();
  }

  // ---- epilogue: e = tanh(acc+bias); l = sum exp(e), c = sum exp(e)*x ----
  // C/D layout: col = lane&15, row = (lane>>4)*4 + reg.
  // acc[m8] rows: wm*128 + (m8>>2)*64 + (m8&3)*16. tanh bounded -> no max sub.
  float lsum[4], csum[4];
#pragma unroll
  for (int nr = 0; nr < 4; nr++) {
    const int o = n0 + wn * 64 + nr * 16 + lr;
    const float bv = bias[o];
    float lacc = 0.f, cacc = 0.f;
#pragma unroll
    for (int m8 = 0; m8 < 8; m8++) {
      const int sr = m0 + wm * 128 + (m8 >> 2) * 64 + (m8 & 3) * 16 + lk * 4;
#pragma unroll
      for (int r = 0; r < 4; r++) {
        float e  = acc[m8][nr][r] + bv;
        float t  = __expf(2.f * e);
        float th = 1.f - __fdividef(2.f, t + 1.f);  // tanh(e); e bounded ~[-7,7]
        float sc = __expf(th);                      // in [0.37, 2.72]
        float xv = bf2f(Xb[(size_t)(sr + r) * Kdim + o]);  // L2-warm
        lacc += sc;
        cacc += sc * xv;
      }
    }
    lacc += __shfl_xor(lacc, 16); lacc += __shfl_xor(lacc, 32);
    cacc += __shfl_xor(cacc, 16); cacc += __shfl_xor(cacc, 32);
    lsum[nr] = lacc; csum[nr] = cacc;
  }

  if (lk == 0) {
#pragma unroll
    for (int nr = 0; nr < 4; nr++) {
      red[wm][0][wn * 64 + nr * 16 + lr] = lsum[nr];
      red[wm][1][wn * 64 + nr * 16 + lr] = csum[nr];
    }
  }
  __syncthreads();
  if (tid < BN2) {
    float L = red[0][0][tid] + red[1][0][tid];
    float C = red[0][1][tid] + red[1][1][tid];
    lpart[(size_t)mt * Ndim + n0 + tid] = L;
    cpart[(size_t)mt * Ndim + n0 + tid] = C;
  }
}

// ---- kernel 3: combine 16 s-chunks -> out[b][o] ----
__global__ __launch_bounds__(256) void finalize_kernel(const float* __restrict__ lpart,
                                                       const float* __restrict__ cpart,
                                                       float* __restrict__ out) {
  int i = blockIdx.x * 256 + threadIdx.x;
  int b = i >> 10, o = i & 1023;
  float L = 0.f, C = 0.f;
#pragma unroll 4
  for (int sc = 0; sc < Sdim / BM2; ++sc) {
    size_t idx = (size_t)(b * (Sdim / BM2) + sc) * Ndim + o;
    L += lpart[idx];
    C += cpart[idx];
  }
  out[i] = C / L;
}

extern "C" void kernel_launch(void* const* d_in, const int* in_sizes, int n_in,
                              void* d_out, int out_size, void* d_ws, size_t ws_size,
                              hipStream_t stream) {
  const float* X    = (const float*)d_in[0];
  const float* W    = (const float*)d_in[1];
  const float* bias = (const float*)d_in[2];
  float* out = (float*)d_out;

  // ws: Xb bf16 (134 MB) | Wb bf16 (2 MB) | lpart (1 MB) | cpart (1 MB)
  const size_t xb_bytes = (size_t)Mtot * Kdim * 2;
  const size_t wb_bytes = (size_t)Ndim * Kdim * 2;
  unsigned short* Xb = (unsigned short*)d_ws;
  unsigned short* Wb = (unsigned short*)((char*)d_ws + xb_bytes);
  float* lpart = (float*)((char*)d_ws + xb_bytes + wb_bytes);
  float* cpart = lpart + (size_t)MT2 * Ndim;

  conv_kernel<<<dim3(XCONV_BLKS + WCONV_BLKS), dim3(256), 0, stream>>>(X, W, Xb, Wb);
  attn_main<<<dim3(MT2 * NT2), dim3(512), 0, stream>>>(Xb, Wb, bias, lpart, cpart);
  finalize_kernel<<<dim3(Bsz * Hdim / 256), dim3(256), 0, stream>>>(lpart, cpart, out);
}